// Round 1
// baseline (384.458 us; speedup 1.0000x reference)
//
#include <hip/hip_runtime.h>

#define NCELLS 2097152  // 128^3

// ---------------- helpers ----------------
__device__ __forceinline__ float2 cadd(float2 a, float2 b){ return make_float2(a.x+b.x, a.y+b.y); }
__device__ __forceinline__ float2 csub(float2 a, float2 b){ return make_float2(a.x-b.x, a.y-b.y); }

// Stockham radix-2 FFT stages over L lines of 128 complex in LDS (ping-pong).
// 64 butterfly tasks per line per stage; 256-thread block. Returns final buffer idx.
// DIR = -1 forward (e^{-i}), +1 inverse (e^{+i}, unnormalized).
template<int DIR, int L, int LDIM>
__device__ __forceinline__ int fft_stages(float2 (*sm)[L][LDIM], int tid) {
  int cur = 0;
  #pragma unroll
  for (int s = 0; s < 7; s++) {
    const int Ns = 1 << s;
    for (int t = tid; t < L * 64; t += 256) {
      int line = t >> 6, j = t & 63;
      float2 a = sm[cur][line][j];
      float2 b = sm[cur][line][j + 64];
      int k = j & (Ns - 1);
      float ang = (float)DIR * 3.14159265358979323f * (float)k / (float)Ns;
      float sn, cs;
      __sincosf(ang, &sn, &cs);
      float2 wb = make_float2(cs * b.x - sn * b.y, cs * b.y + sn * b.x);
      int ob = ((j >> s) << (s + 1)) + k;
      sm[cur ^ 1][line][ob]      = cadd(a, wb);
      sm[cur ^ 1][line][ob + Ns] = csub(a, wb);
    }
    cur ^= 1;
    __syncthreads();
  }
  return cur;
}

// ---------------- rasterization ----------------
__global__ __launch_bounds__(256) void raster_kernel(const float* __restrict__ pts,
                                                     const float* __restrict__ nrm,
                                                     float* __restrict__ vr, int npts) {
  int i = blockIdx.x * 256 + threadIdx.x;
  if (i >= npts) return;
  float tx = pts[3*i+0] * 128.0f, ty = pts[3*i+1] * 128.0f, tz = pts[3*i+2] * 128.0f;
  float nx = nrm[3*i+0], ny = nrm[3*i+1], nz = nrm[3*i+2];
  int lx = (int)floorf(tx), ly = (int)floorf(ty), lz = (int)floorf(tz);
  float fx = tx - (float)lx, fy = ty - (float)ly, fz = tz - (float)lz;
  lx &= 127; ly &= 127; lz &= 127;
  int hx = (lx + 1) & 127, hy = (ly + 1) & 127, hz = (lz + 1) & 127;
  #pragma unroll
  for (int c = 0; c < 8; c++) {
    int ix = (c & 4) ? hx : lx; float wx = (c & 4) ? fx : 1.0f - fx;
    int iy = (c & 2) ? hy : ly; float wy = (c & 2) ? fy : 1.0f - fy;
    int iz = (c & 1) ? hz : lz; float wz = (c & 1) ? fz : 1.0f - fz;
    int idx = (ix << 14) + (iy << 7) + iz;
    float w = wx * wy * wz;
    atomicAdd(vr + idx,              w * nx);
    atomicAdd(vr + NCELLS + idx,     w * ny);
    atomicAdd(vr + 2 * NCELLS + idx, w * nz);
  }
}

// ---------------- FFT kernels ----------------
// z-axis forward, real input -> complex output. 4 contiguous lines per block.
__global__ __launch_bounds__(256) void fft_z_r2c(const float* __restrict__ vin,
                                                 float2* __restrict__ d) {
  __shared__ float2 sm[2][4][128];
  int tid = threadIdx.x;
  int base = blockIdx.x * 512;
  for (int e = tid; e < 512; e += 256)
    sm[0][e >> 7][e & 127] = make_float2(vin[base + e], 0.0f);
  __syncthreads();
  int cur = fft_stages<-1, 4, 128>(sm, tid);
  for (int e = tid; e < 512; e += 256)
    d[base + e] = sm[cur][e >> 7][e & 127];
}

// z-axis complex in-place (used for inverse).
template<int DIR>
__global__ __launch_bounds__(256) void fft_contig(float2* __restrict__ d) {
  __shared__ float2 sm[2][4][128];
  int tid = threadIdx.x;
  int base = blockIdx.x * 512;
  for (int e = tid; e < 512; e += 256)
    sm[0][e >> 7][e & 127] = d[base + e];
  __syncthreads();
  int cur = fft_stages<DIR, 4, 128>(sm, tid);
  for (int e = tid; e < 512; e += 256)
    d[base + e] = sm[cur][e >> 7][e & 127];
}

// strided axis (y: estride=128, astride=16384; x: estride=16384, astride=128).
// Block handles 16 lines at consecutive z (unit stride) for coalescing.
template<int DIR>
__global__ __launch_bounds__(256) void fft_strided(float2* __restrict__ d,
                                                   int estride, int astride) {
  __shared__ float2 sm[2][16][129];  // pad 129: lines land on distinct banks
  int tid = threadIdx.x;
  int base = blockIdx.z * NCELLS + blockIdx.y * astride + blockIdx.x * 16;
  for (int e = tid; e < 2048; e += 256) {
    int line = e & 15, j = e >> 4;
    sm[0][line][j] = d[base + j * estride + line];
  }
  __syncthreads();
  int cur = fft_stages<DIR, 16, 129>(sm, tid);
  for (int e = tid; e < 2048; e += 256) {
    int line = e & 15, j = e >> 4;
    d[base + j * estride + line] = sm[cur][line][j];
  }
}

// ---------------- spectral solve ----------------
__global__ __launch_bounds__(256) void spectral(float2* __restrict__ C) {
  int i = blockIdx.x * 256 + threadIdx.x;
  int z = i & 127, y = (i >> 7) & 127, x = i >> 14;
  float fx = (float)(x < 64 ? x : x - 128);
  float fy = (float)(y < 64 ? y : y - 128);
  float fz = (float)(z < 64 ? z : z - 128);
  float u2 = fx * fx + fy * fy + fz * fz;
  float g = __expf(-0.0030517578125f * u2);  // -2*(5/128)^2 * u2
  float2 v0 = C[i], v1 = C[i + NCELLS], v2 = C[i + 2 * NCELLS];
  float dre = fx * v0.x + fy * v1.x + fz * v2.x;
  float dim = fx * v0.y + fy * v1.y + fz * v2.y;
  // chi = (-i/(2pi)) * g * dot/(u2+eps) * (1/N^3)  ; (-i)*(a+bi) = (b, -a)
  float coef = g / (6.28318530717958648f * (u2 + 1e-6f)) * (1.0f / 2097152.0f);
  C[i] = make_float2(coef * dim, -coef * dre);
}

// ---------------- interpolation + mean ----------------
__global__ __launch_bounds__(256) void interp_mean(const float* __restrict__ pts,
                                                   const float2* __restrict__ C0,
                                                   float* __restrict__ sum, int npts) {
  int i = blockIdx.x * 256 + threadIdx.x;
  float v = 0.0f;
  if (i < npts) {
    float tx = pts[3*i+0] * 128.0f, ty = pts[3*i+1] * 128.0f, tz = pts[3*i+2] * 128.0f;
    int lx = (int)floorf(tx), ly = (int)floorf(ty), lz = (int)floorf(tz);
    float fx = tx - (float)lx, fy = ty - (float)ly, fz = tz - (float)lz;
    lx &= 127; ly &= 127; lz &= 127;
    int hx = (lx + 1) & 127, hy = (ly + 1) & 127, hz = (lz + 1) & 127;
    #pragma unroll
    for (int c = 0; c < 8; c++) {
      int ix = (c & 4) ? hx : lx; float wx = (c & 4) ? fx : 1.0f - fx;
      int iy = (c & 2) ? hy : ly; float wy = (c & 2) ? fy : 1.0f - fy;
      int iz = (c & 1) ? hz : lz; float wz = (c & 1) ? fz : 1.0f - fz;
      v += wx * wy * wz * C0[(ix << 14) + (iy << 7) + iz].x;
    }
  }
  // wave-64 reduction, one atomic per wave
  #pragma unroll
  for (int off = 32; off > 0; off >>= 1) v += __shfl_down(v, off, 64);
  if ((threadIdx.x & 63) == 0) atomicAdd(sum, v);
}

// ---------------- finalize ----------------
__global__ __launch_bounds__(256) void finalize(const float2* __restrict__ C0,
                                                const float* __restrict__ sum,
                                                float* __restrict__ out, int npts) {
  int i = blockIdx.x * 256 + threadIdx.x;
  float mean = sum[0] / (float)npts;
  float chi0 = C0[0].x - mean;
  float scale = 0.5f / fabsf(chi0);
  out[i] = scale * (C0[i].x - mean);
}

// ---------------- launch ----------------
extern "C" void kernel_launch(void* const* d_in, const int* in_sizes, int n_in,
                              void* d_out, int out_size, void* d_ws, size_t ws_size,
                              hipStream_t stream) {
  const float* pts = (const float*)d_in[0];
  const float* nrm = (const float*)d_in[1];
  float* out = (float*)d_out;
  int npts = in_sizes[0] / 3;  // 131072

  // workspace layout: C (3 ch complex, 50.3 MB) | vr (3 ch real, 25.2 MB) | sum (4 B)
  float2* C  = (float2*)d_ws;
  float*  vr = (float*)((char*)d_ws + 3ull * NCELLS * sizeof(float2));
  float*  sum = (float*)((char*)d_ws + 3ull * NCELLS * sizeof(float2)
                                     + 3ull * NCELLS * sizeof(float));

  hipMemsetAsync(vr, 0, 3ull * NCELLS * sizeof(float), stream);
  hipMemsetAsync(sum, 0, sizeof(float), stream);

  raster_kernel<<<(npts + 255) / 256, 256, 0, stream>>>(pts, nrm, vr, npts);

  // forward FFT: z (r2c), y, x — all 3 channels, in place in C
  fft_z_r2c<<<3 * NCELLS / 512, 256, 0, stream>>>(vr, C);
  fft_strided<-1><<<dim3(8, 128, 3), 256, 0, stream>>>(C, 128, 16384);   // y
  fft_strided<-1><<<dim3(8, 128, 3), 256, 0, stream>>>(C, 16384, 128);   // x

  spectral<<<NCELLS / 256, 256, 0, stream>>>(C);

  // inverse FFT on channel 0 (normalization folded into spectral coef)
  fft_contig<1><<<NCELLS / 512, 256, 0, stream>>>(C);                    // z
  fft_strided<1><<<dim3(8, 128, 1), 256, 0, stream>>>(C, 128, 16384);    // y
  fft_strided<1><<<dim3(8, 128, 1), 256, 0, stream>>>(C, 16384, 128);    // x

  interp_mean<<<(npts + 255) / 256, 256, 0, stream>>>(pts, C, sum, npts);
  finalize<<<NCELLS / 256, 256, 0, stream>>>(C, sum, out, npts);
}

// Round 2
// 269.801 us; speedup vs baseline: 1.4250x; 1.4250x over previous
//
#include <hip/hip_runtime.h>

#define NCELLS 2097152  // 128^3

// ---------------- helpers ----------------
__device__ __forceinline__ float2 cadd(float2 a, float2 b){ return make_float2(a.x+b.x, a.y+b.y); }
__device__ __forceinline__ float2 csub(float2 a, float2 b){ return make_float2(a.x-b.x, a.y-b.y); }

// Stockham radix-2 FFT stages over L lines of 128 complex in LDS (ping-pong).
template<int DIR, int L, int LDIM>
__device__ __forceinline__ int fft_stages(float2 (*sm)[L][LDIM], int tid) {
  int cur = 0;
  #pragma unroll
  for (int s = 0; s < 7; s++) {
    const int Ns = 1 << s;
    for (int t = tid; t < L * 64; t += 256) {
      int line = t >> 6, j = t & 63;
      float2 a = sm[cur][line][j];
      float2 b = sm[cur][line][j + 64];
      int k = j & (Ns - 1);
      float ang = (float)DIR * 3.14159265358979323f * (float)k / (float)Ns;
      float sn, cs;
      __sincosf(ang, &sn, &cs);
      float2 wb = make_float2(cs * b.x - sn * b.y, cs * b.y + sn * b.x);
      int ob = ((j >> s) << (s + 1)) + k;
      sm[cur ^ 1][line][ob]      = cadd(a, wb);
      sm[cur ^ 1][line][ob + Ns] = csub(a, wb);
    }
    cur ^= 1;
    __syncthreads();
  }
  return cur;
}

// ---------------- raster path: bin by (x,y) column ----------------
__global__ __launch_bounds__(256) void hist_kernel(const float* __restrict__ pts,
                                                   int* __restrict__ counts, int npts) {
  int i = blockIdx.x * 256 + threadIdx.x;
  if (i >= npts) return;
  int lx = ((int)floorf(pts[3*i+0] * 128.0f)) & 127;
  int ly = ((int)floorf(pts[3*i+1] * 128.0f)) & 127;
  atomicAdd(counts + ((lx << 7) + ly), 1);
}

// single-block exclusive scan over 16384 counters -> off[16385], cur[16384]
__global__ __launch_bounds__(1024) void scan16k(const int* __restrict__ counts,
                                                int* __restrict__ off,
                                                int* __restrict__ cur) {
  __shared__ int part[1024];
  int t = threadIdx.x;
  int local[16]; int s = 0;
  #pragma unroll
  for (int k = 0; k < 16; k++) { local[k] = s; s += counts[t * 16 + k]; }
  part[t] = s;
  __syncthreads();
  for (int d = 1; d < 1024; d <<= 1) {
    int v = (t >= d) ? part[t - d] : 0;
    __syncthreads();
    part[t] += v;
    __syncthreads();
  }
  int base = (t == 0) ? 0 : part[t - 1];
  #pragma unroll
  for (int k = 0; k < 16; k++) {
    int o = base + local[k];
    off[t * 16 + k] = o;
    cur[t * 16 + k] = o;
  }
  if (t == 1023) off[16384] = part[1023];
}

__global__ __launch_bounds__(256) void scatter_kernel(const float* __restrict__ pts,
                                                      const float* __restrict__ nrm,
                                                      int* __restrict__ cur,
                                                      float4* __restrict__ sorted, int npts) {
  int i = blockIdx.x * 256 + threadIdx.x;
  if (i >= npts) return;
  float px = pts[3*i+0], py = pts[3*i+1], pz = pts[3*i+2];
  int lx = ((int)floorf(px * 128.0f)) & 127;
  int ly = ((int)floorf(py * 128.0f)) & 127;
  int slot = atomicAdd(cur + ((lx << 7) + ly), 1);
  sorted[2*slot]   = make_float4(px, py, pz, 0.0f);
  sorted[2*slot+1] = make_float4(nrm[3*i+0], nrm[3*i+1], nrm[3*i+2], 0.0f);
}

// one block per (x,y) column: gather 4 neighbor buckets, accumulate z-column in LDS.
__global__ __launch_bounds__(128) void raster_cols(const float4* __restrict__ sorted,
                                                   const int* __restrict__ off,
                                                   float* __restrict__ vr) {
  int col = blockIdx.x;            // x*128 + y
  int x = col >> 7, y = col & 127;
  __shared__ float acc[3][128];
  for (int t = threadIdx.x; t < 384; t += 128) ((float*)acc)[t] = 0.0f;
  __syncthreads();
  #pragma unroll
  for (int q = 0; q < 4; q++) {
    int bx = (q & 2) ? x : (x + 127) & 127;  // bx==x -> lo-x corner (weight 1-fx)
    int by = (q & 1) ? y : (y + 127) & 127;
    int b = (bx << 7) + by;
    int s = off[b], e = off[b + 1];
    for (int p = s + threadIdx.x; p < e; p += 128) {
      float4 P  = sorted[2*p];
      float4 Nm = sorted[2*p+1];
      float tx = P.x * 128.0f, ty = P.y * 128.0f, tz = P.z * 128.0f;
      float fx = tx - floorf(tx), fy = ty - floorf(ty), fz = tz - floorf(tz);
      int lz = ((int)floorf(tz)) & 127;
      int z1 = (lz + 1) & 127;
      float wx = (q & 2) ? (1.0f - fx) : fx;
      float wy = (q & 1) ? (1.0f - fy) : fy;
      float w0 = wx * wy * (1.0f - fz), w1 = wx * wy * fz;
      atomicAdd(&acc[0][lz], w0 * Nm.x); atomicAdd(&acc[0][z1], w1 * Nm.x);
      atomicAdd(&acc[1][lz], w0 * Nm.y); atomicAdd(&acc[1][z1], w1 * Nm.y);
      atomicAdd(&acc[2][lz], w0 * Nm.z); atomicAdd(&acc[2][z1], w1 * Nm.z);
    }
  }
  __syncthreads();
  int base = col << 7;
  for (int t = threadIdx.x; t < 384; t += 128) {
    int c = t >> 7, z = t & 127;
    vr[c * NCELLS + base + z] = acc[c][z];
  }
}

// ---------------- FFT kernels ----------------
__global__ __launch_bounds__(256) void fft_z_r2c(const float* __restrict__ vin,
                                                 float2* __restrict__ d) {
  __shared__ float2 sm[2][4][128];
  int tid = threadIdx.x;
  int base = blockIdx.x * 512;
  for (int e = tid; e < 512; e += 256)
    sm[0][e >> 7][e & 127] = make_float2(vin[base + e], 0.0f);
  __syncthreads();
  int cur = fft_stages<-1, 4, 128>(sm, tid);
  for (int e = tid; e < 512; e += 256)
    d[base + e] = sm[cur][e >> 7][e & 127];
}

template<int DIR>
__global__ __launch_bounds__(256) void fft_contig(float2* __restrict__ d) {
  __shared__ float2 sm[2][4][128];
  int tid = threadIdx.x;
  int base = blockIdx.x * 512;
  for (int e = tid; e < 512; e += 256)
    sm[0][e >> 7][e & 127] = d[base + e];
  __syncthreads();
  int cur = fft_stages<DIR, 4, 128>(sm, tid);
  for (int e = tid; e < 512; e += 256)
    d[base + e] = sm[cur][e >> 7][e & 127];
}

template<int DIR>
__global__ __launch_bounds__(256) void fft_strided(float2* __restrict__ d,
                                                   int estride, int astride) {
  __shared__ float2 sm[2][16][129];
  int tid = threadIdx.x;
  int base = blockIdx.z * NCELLS + blockIdx.y * astride + blockIdx.x * 16;
  for (int e = tid; e < 2048; e += 256) {
    int line = e & 15, j = e >> 4;
    sm[0][line][j] = d[base + j * estride + line];
  }
  __syncthreads();
  int cur = fft_stages<DIR, 16, 129>(sm, tid);
  for (int e = tid; e < 2048; e += 256) {
    int line = e & 15, j = e >> 4;
    d[base + j * estride + line] = sm[cur][line][j];
  }
}

// ---------------- spectral solve ----------------
__global__ __launch_bounds__(256) void spectral(float2* __restrict__ C) {
  int i = blockIdx.x * 256 + threadIdx.x;
  int z = i & 127, y = (i >> 7) & 127, x = i >> 14;
  float fx = (float)(x < 64 ? x : x - 128);
  float fy = (float)(y < 64 ? y : y - 128);
  float fz = (float)(z < 64 ? z : z - 128);
  float u2 = fx * fx + fy * fy + fz * fz;
  float g = __expf(-0.0030517578125f * u2);
  float2 v0 = C[i], v1 = C[i + NCELLS], v2 = C[i + 2 * NCELLS];
  float dre = fx * v0.x + fy * v1.x + fz * v2.x;
  float dim = fx * v0.y + fy * v1.y + fz * v2.y;
  float coef = g / (6.28318530717958648f * (u2 + 1e-6f)) * (1.0f / 2097152.0f);
  C[i] = make_float2(coef * dim, -coef * dre);
}

// ---------------- interpolation + mean ----------------
__global__ __launch_bounds__(256) void interp_mean(const float* __restrict__ pts,
                                                   const float2* __restrict__ C0,
                                                   float* __restrict__ sum, int npts) {
  int i = blockIdx.x * 256 + threadIdx.x;
  float v = 0.0f;
  if (i < npts) {
    float tx = pts[3*i+0] * 128.0f, ty = pts[3*i+1] * 128.0f, tz = pts[3*i+2] * 128.0f;
    int lx = (int)floorf(tx), ly = (int)floorf(ty), lz = (int)floorf(tz);
    float fx = tx - (float)lx, fy = ty - (float)ly, fz = tz - (float)lz;
    lx &= 127; ly &= 127; lz &= 127;
    int hx = (lx + 1) & 127, hy = (ly + 1) & 127, hz = (lz + 1) & 127;
    #pragma unroll
    for (int c = 0; c < 8; c++) {
      int ix = (c & 4) ? hx : lx; float wx = (c & 4) ? fx : 1.0f - fx;
      int iy = (c & 2) ? hy : ly; float wy = (c & 2) ? fy : 1.0f - fy;
      int iz = (c & 1) ? hz : lz; float wz = (c & 1) ? fz : 1.0f - fz;
      v += wx * wy * wz * C0[(ix << 14) + (iy << 7) + iz].x;
    }
  }
  #pragma unroll
  for (int off = 32; off > 0; off >>= 1) v += __shfl_down(v, off, 64);
  if ((threadIdx.x & 63) == 0) atomicAdd(sum, v);
}

// ---------------- finalize ----------------
__global__ __launch_bounds__(256) void finalize(const float2* __restrict__ C0,
                                                const float* __restrict__ sum,
                                                float* __restrict__ out, int npts) {
  int i = blockIdx.x * 256 + threadIdx.x;
  float mean = sum[0] / (float)npts;
  float chi0 = C0[0].x - mean;
  float scale = 0.5f / fabsf(chi0);
  out[i] = scale * (C0[i].x - mean);
}

// ---------------- launch ----------------
extern "C" void kernel_launch(void* const* d_in, const int* in_sizes, int n_in,
                              void* d_out, int out_size, void* d_ws, size_t ws_size,
                              hipStream_t stream) {
  const float* pts = (const float*)d_in[0];
  const float* nrm = (const float*)d_in[1];
  float* out = (float*)d_out;
  int npts = in_sizes[0] / 3;  // 131072

  // workspace layout:
  //   C       : 3ch complex grid, 50.3 MB   (also aliases nothing live during raster)
  //   vr      : 3ch real grid, 25.2 MB
  //   sorted  : binned points, 2*float4 per point, 4.2 MB
  //   counts/off/cur/sum : small
  char* w = (char*)d_ws;
  float2* C      = (float2*)w;                                   w += 3ull*NCELLS*sizeof(float2);
  float*  vr     = (float*)w;                                    w += 3ull*NCELLS*sizeof(float);
  float4* sorted = (float4*)w;                                   w += 2ull*131072*sizeof(float4);
  int*    counts = (int*)w;                                      w += 16384*sizeof(int);
  int*    off    = (int*)w;                                      w += 16385*sizeof(int);
  int*    cur    = (int*)w;                                      w += 16384*sizeof(int);
  float*  sum    = (float*)w;

  hipMemsetAsync(counts, 0, 16384*sizeof(int), stream);
  hipMemsetAsync(sum, 0, sizeof(float), stream);

  hist_kernel<<<(npts + 255) / 256, 256, 0, stream>>>(pts, counts, npts);
  scan16k<<<1, 1024, 0, stream>>>(counts, off, cur);
  scatter_kernel<<<(npts + 255) / 256, 256, 0, stream>>>(pts, nrm, cur, sorted, npts);
  raster_cols<<<16384, 128, 0, stream>>>(sorted, off, vr);

  // forward FFT: z (r2c), y, x — all 3 channels, in place in C
  fft_z_r2c<<<3 * NCELLS / 512, 256, 0, stream>>>(vr, C);
  fft_strided<-1><<<dim3(8, 128, 3), 256, 0, stream>>>(C, 128, 16384);   // y
  fft_strided<-1><<<dim3(8, 128, 3), 256, 0, stream>>>(C, 16384, 128);   // x

  spectral<<<NCELLS / 256, 256, 0, stream>>>(C);

  // inverse FFT on channel 0 (normalization folded into spectral coef)
  fft_contig<1><<<NCELLS / 512, 256, 0, stream>>>(C);                    // z
  fft_strided<1><<<dim3(8, 128, 1), 256, 0, stream>>>(C, 128, 16384);    // y
  fft_strided<1><<<dim3(8, 128, 1), 256, 0, stream>>>(C, 16384, 128);    // x

  interp_mean<<<(npts + 255) / 256, 256, 0, stream>>>(pts, C, sum, npts);
  finalize<<<NCELLS / 256, 256, 0, stream>>>(C, sum, out, npts);
}